// Round 3
// baseline (587.821 us; speedup 1.0000x reference)
//
#include <hip/hip_runtime.h>

// CSTR gated-estimator trajectory cost — 2 lanes per sample, 4 samples per
// lane-pair (chain interleave). B=8192, T=2048 sequential RK4 steps, N=2.
//
// Regime evidence (rounds 0-2): latency-bound on the per-step dependency
// chain. Round 1 (2.5x per-lane ops) and round 2 (shorter chain) both moved
// per-step time by <12% -> wall = T x chain latency, no TLP (1 wave/CU,
// lockstep SIMT), no cross-step ILP. Fix: C=4 independent samples per lane
// pair -> 4 interleaved dependency chains in one instruction stream. The
// step body is the round-0 variant verbatim (fastest measured, 188 cyc/step).
//
// RK4 collapsed analytically (affine plant):
//   x_own' = (1-2H) x_own + H x_other + H u + C_own + w_own,
//   C_1 = +H^2/2, C_2 = -H^2. Sigmoid in exp2 domain (phi coeffs * -log2(e)).

#define T_STEPS 2048
#define BATCH   8192
#define NC      4      // chains (samples) per lane-pair

__device__ __forceinline__ float swapf(float v) {
    // quad_perm [1,0,3,2]: swap adjacent lane pairs. bound_ctrl=1, full masks.
    return __int_as_float(__builtin_amdgcn_update_dpp(
        0, __float_as_int(v), 0xB1, 0xF, 0xF, true));
}

__global__ __launch_bounds__(64, 1) void cstr_kernel(
    const float* __restrict__ w,   // (B, 2, T)
    const float* __restrict__ K,   // (1, 2)
    const float* __restrict__ L,   // (4, 4)
    const float* __restrict__ M,   // (1, 4)
    const float* __restrict__ Mo,  // (1, 1)
    float* __restrict__ out)       // (B,)
{
    const int lane = threadIdx.x;
    const int p = lane & 1;                 // owned state index
    const int pairid = lane >> 1;           // 0..31
    const int sbase = blockIdx.x * (32 * NC) + pairid;

    // ---- uniform scalars ----
    const float k1c = K[0], k2c = K[1];
    const float s11 = L[0];
    const float s12 = L[1] + L[4];
    const float s13 = L[2] + L[8];
    const float s14 = L[3] + L[12];
    const float s22 = L[5];
    const float s23 = L[6] + L[9];
    const float s24 = L[7] + L[13];
    const float s33 = L[10];
    const float s34 = L[11] + L[14];
    const float s44 = L[15];
    const float m1 = M[0], m2 = M[1], m3 = M[2], m4 = M[3];
    const float c0 = Mo[0];

    constexpr float Hs = 0.01f;
    constexpr float Ad = 1.0f - 2.0f * Hs;           // 0.98
    constexpr float Rc = 0.1f;
    constexpr float SC = -1.44269504088896340736f;   // -log2(e)

    // per-lane phi partial coefficients (see round-0 derivation)
    float P1, P2, P3, P4, P5, P6, P7, P8;
    if (p == 0) { P1 = s11; P2 = s12; P3 = s13; P4 = s14; P5 = m1; P6 = s33; P7 = s34; P8 = m3; }
    else        { P1 = s22; P2 = 0.f; P3 = s24; P4 = s23; P5 = m2; P6 = s44; P7 = 0.f; P8 = m4; }
    P1 *= SC; P2 *= SC; P3 *= SC; P4 *= SC; P5 *= SC; P6 *= SC; P7 *= SC; P8 *= SC;
    const float P9 = 0.5f * c0 * SC;

    const float kown = p ? k2c : k1c;
    const float koth = p ? k1c : k2c;
    const float hk   = Hs * kown;                     // H * K_own
    const float Cown = p ? (-Hs * Hs) : (0.5f * Hs * Hs);

    // ---- per-chain state ----
    float x[NC], xh[NC], accO[NC], accD[NC];
    #pragma unroll
    for (int c = 0; c < NC; ++c) {
        x[c] = p ? 0.0f : 1.0f;   // x0 = (1, 0)
        xh[c] = x[c];
        accO[c] = 0.0f;
        accD[c] = 0.0f;
    }

    // one generic step (round-0 body, fastest measured)
    auto step = [&](int c, float wv, bool first, bool cost) {
        float xo  = swapf(x[c]);
        float xho = swapf(xh[c]);
        float d;
        if (first) {
            d = 1.0f;              // i==0: gate forced, x_hat frozen (x==xh)
        } else {
            float t  = fmaf(P2, xo, fmaf(P1, x[c], P5));
            t        = fmaf(P3, xh[c], t);
            t        = fmaf(P4, xho, t);
            float u2 = fmaf(P7, xho, fmaf(P6, xh[c], P8));
            float part = fmaf(xh[c], u2, fmaf(x[c], t, P9));
            float e  = __builtin_amdgcn_exp2f(part + swapf(part)); // = exp(-phi)
            d        = __builtin_amdgcn_rcpf(1.0f + e);
            xh[c]    = fmaf(d, x[c] - xh[c], xh[c]);
        }
        if (cost) {                 // stage cost uses PRE-update x, this step's d
            float us = fmaf(kown, x[c], koth * xo);
            accO[c] = fmaf(x[c], x[c], accO[c]);
            accD[c] = fmaf(Rc * us, us, accD[c]);
            accD[c] += d;
        }
        float pown = hk * xh[c];    // H*u split: hu = H*(k1*xh1' + k2*xh2')
        float hu   = pown + swapf(pown);
        x[c] = fmaf(Ad, x[c], fmaf(Hs, xo, wv + Cown)) + hu;
    };

    // chunk = 8 steps (2 float4 per chain), chains interleaved per w-element
    auto chunk = [&](float4 (&buf)[NC][2], bool first, bool lastchunk) {
        #pragma unroll
        for (int q = 0; q < 2; ++q) {
            #pragma unroll
            for (int c = 0; c < NC; ++c) step(c, buf[c][q].x, first && (q == 0), true);
            #pragma unroll
            for (int c = 0; c < NC; ++c) step(c, buf[c][q].y, false, true);
            #pragma unroll
            for (int c = 0; c < NC; ++c) step(c, buf[c][q].z, false, true);
            #pragma unroll
            for (int c = 0; c < NC; ++c) step(c, buf[c][q].w, false,
                                              !(lastchunk && (q == 1)));
        }
    };

    // per-chain own-row stream: T floats = 512 float4 = 256 chunks of 8 steps
    const float4* r[NC];
    #pragma unroll
    for (int c = 0; c < NC; ++c) {
        int s = sbase + c * 32;
        r[c] = reinterpret_cast<const float4*>(w + ((size_t)s * 2 + p) * T_STEPS);
    }

    float4 A[NC][2], Bb[NC][2];
    #pragma unroll
    for (int c = 0; c < NC; ++c) { A[c][0]  = r[c][0]; A[c][1]  = r[c][1]; }
    #pragma unroll
    for (int c = 0; c < NC; ++c) { Bb[c][0] = r[c][2]; Bb[c][1] = r[c][3]; }

    chunk(A, true, false);                             // chunk 0 (step 0 special)

    for (int i = 0; i < 127; ++i) {                    // chunks 1..254
        #pragma unroll
        for (int c = 0; c < NC; ++c) {
            const float4* pa = r[c] + (size_t)(2 + 2 * i) * 2;
            A[c][0] = pa[0]; A[c][1] = pa[1];          // prefetch chunk 2+2i
        }
        chunk(Bb, false, false);                       // process chunk 1+2i
        #pragma unroll
        for (int c = 0; c < NC; ++c) {
            const float4* pb = r[c] + (size_t)(3 + 2 * i) * 2;
            Bb[c][0] = pb[0]; Bb[c][1] = pb[1];        // prefetch chunk 3+2i
        }
        chunk(A, false, false);                        // process chunk 2+2i
    }
    chunk(Bb, false, true);                            // chunk 255 (last: no cost)

    // terminal cost 10*(x1^2 + x2^2), split by ownership
    #pragma unroll
    for (int c = 0; c < NC; ++c) {
        float a = fmaf(10.0f * x[c], x[c], accO[c]);
        float J = a + swapf(a) + accD[c];
        if (p == 0) out[sbase + c * 32] = J;
    }
}

extern "C" void kernel_launch(void* const* d_in, const int* in_sizes, int n_in,
                              void* d_out, int out_size, void* d_ws, size_t ws_size,
                              hipStream_t stream) {
    const float* w  = (const float*)d_in[0];
    const float* K  = (const float*)d_in[1];
    const float* L  = (const float*)d_in[2];
    const float* M  = (const float*)d_in[3];
    const float* Mo = (const float*)d_in[4];
    float* out = (float*)d_out;

    // 8192 samples * 2 lanes / 4 chains-per-pair = 4096 threads = 64 blocks of 64
    hipLaunchKernelGGL(cstr_kernel, dim3(BATCH * 2 / (64 * NC)), dim3(64), 0, stream,
                       w, K, L, M, Mo, out);
}

// Round 7
// 323.737 us; speedup vs baseline: 1.8157x; 1.8157x over previous
//
#include <hip/hip_runtime.h>

// CSTR gated-estimator trajectory cost — 2 lanes per sample, delta-expansion.
// B=8192 samples, T=2048 sequential RK4 steps, N=2 states.
//
// Rounds 0-3 established: wall = T x per-step serial chain (188 cyc); chain
// interleaving across samples cannot beat the per-sample latency floor.
// This version shortens the TRUE recurrence algebraically:
//   x_{t+1} = q_t + d_t*g_t,  h_{t+1} = h_t + d_t*dx_t  are AFFINE in d_t,
//   so phi_{t+1} = quad(z_{t+1}) = A_t + B_t d_t + C_t d_t^2  EXACTLY, with
//   A,B,C functions of (x_t,h_t,w_t) only — computable BEFORE d_t resolves.
// Serial chain per step collapses to: d -> 2 fma -> exp2 -> add -> rcp -> d'
// (~50 cyc); the ~32-instr coefficient block is d-independent and issues
// during the trans-pipe latency. Kernel becomes issue-bound (~50 instr/step).
//
// Per-lane expansion (round-0 P-table, phi split part + swap(part)):
//   part = x*t + h*u + P9,  t = P1 x + P2 xo + P3 h + P4 ho + P5,
//                           u = P6 h + P7 ho + P8.
// Substituting x->q+dg, xo->qo+dg, h->h+d dx, ho->ho+d dxo:
//   t = t0 + d t1, u = u0 + d u1,
//   pA = q t0 + h u0 + P9; pB = q t1 + g t0 + h u1 + dx u0; pC = g t1 + dx u1.
// Partner mirrors kept bitwise-exact without on-chain DPP:
//   xo = fma(d,g,qo), ho = fma(d,dxo,ho); hu0c (= H*K.h + Cw) incremental.
// RK4 collapsed analytically; sigmoid in exp2 domain (coeffs * -log2(e)).

#define T_STEPS 2048
#define BATCH   8192

__device__ __forceinline__ float swapf(float v) {
    // quad_perm [1,0,3,2]: swap adjacent lane pairs. bound_ctrl=1, full masks.
    return __int_as_float(__builtin_amdgcn_update_dpp(
        0, __float_as_int(v), 0xB1, 0xF, 0xF, true));
}

__global__ __launch_bounds__(64, 1) void cstr_kernel(
    const float* __restrict__ w,   // (B, 2, T)
    const float* __restrict__ K,   // (1, 2)
    const float* __restrict__ L,   // (4, 4)
    const float* __restrict__ M,   // (1, 4)
    const float* __restrict__ Mo,  // (1, 1)
    float* __restrict__ out)       // (B,)
{
    const int lane = threadIdx.x;
    const int p = lane & 1;                          // owned state index
    const int s = blockIdx.x * 32 + (lane >> 1);     // sample id

    // ---- uniform scalars ----
    const float k1c = K[0], k2c = K[1];
    const float s11 = L[0];
    const float s12 = L[1] + L[4];
    const float s13 = L[2] + L[8];
    const float s14 = L[3] + L[12];
    const float s22 = L[5];
    const float s23 = L[6] + L[9];
    const float s24 = L[7] + L[13];
    const float s33 = L[10];
    const float s34 = L[11] + L[14];
    const float s44 = L[15];
    const float m1 = M[0], m2 = M[1], m3 = M[2], m4 = M[3];
    const float c0 = Mo[0];

    constexpr float Hs = 0.01f;
    constexpr float Ad = 1.0f - 2.0f * Hs;           // 0.98
    constexpr float Rc = 0.1f;
    constexpr float SC = -1.44269504088896340736f;   // -log2(e)

    // per-lane phi partial coefficients (round-0 table, verified)
    float P1, P2, P3, P4, P5, P6, P7, P8;
    if (p == 0) { P1 = s11; P2 = s12; P3 = s13; P4 = s14; P5 = m1; P6 = s33; P7 = s34; P8 = m3; }
    else        { P1 = s22; P2 = 0.f; P3 = s24; P4 = s23; P5 = m2; P6 = s44; P7 = 0.f; P8 = m4; }
    P1 *= SC; P2 *= SC; P3 *= SC; P4 *= SC; P5 *= SC; P6 *= SC; P7 *= SC; P8 *= SC;
    const float P9  = 0.5f * c0 * SC;
    const float P12 = P1 + P2;

    const float kown = p ? k2c : k1c;
    const float Hk   = Hs * kown;                    // H * K_own (g partial)
    const float Cown = p ? (-Hs * Hs) : (0.5f * Hs * Hs);

    // ---- state ----
    float x  = p ? 0.0f : 1.0f;   // x0 = (1, 0)
    float h  = x;
    float xo = p ? 1.0f : 0.0f;   // partner mirrors (bitwise-exact by induction)
    float ho = xo;
    float dx = 0.0f, dxo = 0.0f;
    // hu0c = H*(K.h) + Cw_own; h0=(1,0) -> K.h0 = k1. Incremental: += d*g.
    float hu0c = Hs * k1c + Cown;
    float phi  = 0.0f;            // exp2-domain phi_k (valid from k=1)
    float accO = 0.0f;            // sum own x^2
    float accXY = 0.0f;           // sum x1*x2 (identical on both lanes)
    float accD = 0.0f;            // sum delta (identical on both lanes)

    auto step = [&](float wv, bool first, bool cost) {
        // ---- delta resolution (chain): only exp/add/rcp + prior 2 fma ----
        float d;
        float E = 0.0f;
        if (!first) E = __builtin_amdgcn_exp2f(phi);         // = exp(-phi_k)

        // ---- delta-independent coefficient block (fills trans latency) ----
        float gp  = Hk * dx;
        float g   = gp + swapf(gp);              // H*K.(x-h), uniform scalar
        float wck = wv + hu0c;                   // w + Cw + H*K.h
        float q   = fmaf(Ad, x, fmaf(Hs, xo, wck));
        float qo  = swapf(q);                    // partner's q (exact)
        float t0  = fmaf(P4, ho, fmaf(P3, h, fmaf(P2, qo, fmaf(P1, q, P5))));
        float t1  = fmaf(P12, g, fmaf(P3, dx, P4 * dxo));
        float u0  = fmaf(P7, ho, fmaf(P6, h, P8));
        float u1  = fmaf(P7, dxo, P6 * dx);
        float pA  = fmaf(q, t0, fmaf(h, u0, P9));
        float pB  = fmaf(q, t1, fmaf(g, t0, fmaf(h, u1, dx * u0)));
        float pC  = fmaf(g, t1, dx * u1);
        float Aq  = pA + swapf(pA);              // phi_{k+1} = Aq + Bq d + Cq d^2
        float Bq  = pB + swapf(pB);
        float Cq  = pC + swapf(pC);

        if (first) d = 1.0f;                     // i==0: gate forced
        else       d = __builtin_amdgcn_rcpf(1.0f + E);      // sigmoid(phi_k)

        if (cost) {               // stage cost uses PRE-update x, this step's d
            accO  = fmaf(x, x, accO);
            accXY = fmaf(x, xo, accXY);
            accD += d;
        }
        // next phi from THIS step's coefficients and THIS step's delta
        phi = fmaf(d, fmaf(Cq, d, Bq), Aq);
        // advance state (affine in d); partner mirrors updated bitwise-equal
        x    = fmaf(d, g, q);
        xo   = fmaf(d, g, qo);
        h    = fmaf(d, dx, h);
        ho   = fmaf(d, dxo, ho);
        hu0c = fmaf(d, g, hu0c);
        dx   = x - h;
        dxo  = xo - ho;
    };

    auto chunk = [&](const float4* buf, bool first, bool lastchunk) {
        #pragma unroll
        for (int q = 0; q < 4; ++q) {
            float4 a = buf[q];
            step(a.x, first && (q == 0), true);
            step(a.y, false, true);
            step(a.z, false, true);
            step(a.w, false, !(lastchunk && (q == 3)));  // t=T-1: no stage cost
        }
    };

    // own-row stream: T floats = 512 float4 = 128 chunks of 16 steps
    const float4* r = reinterpret_cast<const float4*>(
        w + ((size_t)s * 2 + p) * T_STEPS);

    float4 Abuf[4], Bbuf[4];
    #pragma unroll
    for (int q = 0; q < 4; ++q) Abuf[q] = r[q];        // chunk 0
    #pragma unroll
    for (int q = 0; q < 4; ++q) Bbuf[q] = r[4 + q];    // chunk 1

    chunk(Abuf, true, false);                          // chunk 0 (step 0 special)

    for (int i = 0; i < 63; ++i) {                     // chunks 1..126
        const float4* pa = r + (size_t)(2 + 2 * i) * 4;
        #pragma unroll
        for (int q = 0; q < 4; ++q) Abuf[q] = pa[q];   // prefetch chunk 2+2i
        chunk(Bbuf, false, false);                     // process chunk 1+2i
        const float4* pb = r + (size_t)(3 + 2 * i) * 4;
        #pragma unroll
        for (int q = 0; q < 4; ++q) Bbuf[q] = pb[q];   // prefetch chunk 3+2i
        chunk(Abuf, false, false);                     // process chunk 2+2i
    }
    chunk(Bbuf, false, true);                          // chunk 127 (last step: no cost)

    // Sum us^2 = k1^2*Sx1^2 + k2^2*Sx2^2 + 2 k1 k2*Sx1x2, assembled pairwise
    float tt  = fmaf(kown * kown, accO, (k1c * k2c) * accXY);
    float us2 = tt + swapf(tt);
    float qq  = accO + swapf(accO);              // Sum (x1^2 + x2^2)
    float term = 10.0f * fmaf(x, x, xo * xo);    // terminal, same on both lanes
    float J = qq + fmaf(Rc, us2, accD + term);
    if (p == 0) out[s] = J;
}

extern "C" void kernel_launch(void* const* d_in, const int* in_sizes, int n_in,
                              void* d_out, int out_size, void* d_ws, size_t ws_size,
                              hipStream_t stream) {
    const float* w  = (const float*)d_in[0];
    const float* K  = (const float*)d_in[1];
    const float* L  = (const float*)d_in[2];
    const float* M  = (const float*)d_in[3];
    const float* Mo = (const float*)d_in[4];
    float* out = (float*)d_out;

    // 8192 samples * 2 lanes = 16384 threads = 256 blocks of 64 (1 wave each)
    hipLaunchKernelGGL(cstr_kernel, dim3(BATCH * 2 / 64), dim3(64), 0, stream,
                       w, K, L, M, Mo, out);
}

// Round 8
// 312.750 us; speedup vs baseline: 1.8795x; 1.0351x over previous
//
#include <hip/hip_runtime.h>

// CSTR gated-estimator trajectory cost — 1 lane/sample, packed-FP32 (VOP3P).
// B=8192 samples, T=2048 sequential RK4 steps, N=2 states.
//
// Empirical per-wave law (fits R0/R1/R2/R7 within 3%):
//   cyc/step = 80 (exp+rcp, latency fully exposed) + 2.6*N_VALU + 12.75*N_DPP.
// => minimize DPP (1 lane/sample: zero cross-lane) and N_VALU (pk ops halve it).
// v_pk_fma_f32/v_pk_mul_f32/v_pk_add_f32 via inline asm; op_sel modifiers give
// free broadcast-lo/hi and swap of src1 (no pair-construction v_movs).
// First-step special case removed: phi0 = -inf -> E=exp2(-inf)=0 -> y=1 ->
// d=rcp(1)=1 exactly (gate forced open at t=0, matching reference).
//
// Math (exact reordering of reference, same liberties as passing rounds):
//   RK4 collapsed: x1' = .98 x1 + .01 x2 + .01 u + H^2/2 + w1
//                  x2' = .98 x2 + .01 x1 + .01 u - H^2   + w2,  u = K.h'
//   h' = h + d (x - h);  d = sigmoid(phi) = rcp(1 + exp(-c0)*exp2(SC*(zUz+mz)))
//   U upper-tri fold of L, all phi coeffs pre-scaled by SC = -log2(e).
//   Cost moments {Sx1^2, Sx2^2, Sx1x2, Sd}; Sum us^2 reconstructed at end.

#define T_STEPS 2048
#define BATCH   8192

typedef float v2f __attribute__((ext_vector_type(2)));

__device__ __forceinline__ v2f mk2(float a, float b) { v2f r; r.x = a; r.y = b; return r; }

// ---- VOP3P packed-fp32 helpers (gfx950). op_sel[i]: src_i half used by LOW
// result; op_sel_hi[i]: half used by HIGH result. Defaults [0,0,0]/[1,1,1]. ----
__device__ __forceinline__ v2f pk_fma(v2f a, v2f b, v2f c) {
    v2f d;
    asm("v_pk_fma_f32 %0, %1, %2, %3" : "=v"(d) : "v"(a), "v"(b), "v"(c));
    return d;
}
__device__ __forceinline__ v2f pk_fma_b1lo(v2f a, v2f b, v2f c) { // src1.lo both halves
    v2f d;
    asm("v_pk_fma_f32 %0, %1, %2, %3 op_sel:[0,0,0] op_sel_hi:[1,0,1]"
        : "=v"(d) : "v"(a), "v"(b), "v"(c));
    return d;
}
__device__ __forceinline__ v2f pk_fma_b1hi(v2f a, v2f b, v2f c) { // src1.hi both halves
    v2f d;
    asm("v_pk_fma_f32 %0, %1, %2, %3 op_sel:[0,1,0] op_sel_hi:[1,1,1]"
        : "=v"(d) : "v"(a), "v"(b), "v"(c));
    return d;
}
__device__ __forceinline__ v2f pk_fma_b1swap(v2f a, v2f b, v2f c) { // src1 halves swapped
    v2f d;
    asm("v_pk_fma_f32 %0, %1, %2, %3 op_sel:[0,1,0] op_sel_hi:[1,0,1]"
        : "=v"(d) : "v"(a), "v"(b), "v"(c));
    return d;
}
__device__ __forceinline__ v2f pk_mul(v2f a, v2f b) {
    v2f d;
    asm("v_pk_mul_f32 %0, %1, %2" : "=v"(d) : "v"(a), "v"(b));
    return d;
}
__device__ __forceinline__ v2f pk_add(v2f a, v2f b) {
    v2f d;
    asm("v_pk_add_f32 %0, %1, %2" : "=v"(d) : "v"(a), "v"(b));
    return d;
}
__device__ __forceinline__ v2f pk_hadd(v2f a) { // (lo+hi, hi+lo)
    v2f d;
    asm("v_pk_add_f32 %0, %1, %2 op_sel:[0,1] op_sel_hi:[1,0]"
        : "=v"(d) : "v"(a), "v"(a));
    return d;
}

__global__ __launch_bounds__(64, 1) void cstr_kernel(
    const float* __restrict__ w,   // (B, 2, T)
    const float* __restrict__ K,   // (1, 2)
    const float* __restrict__ L,   // (4, 4)
    const float* __restrict__ M,   // (1, 4)
    const float* __restrict__ Mo,  // (1, 1)
    float* __restrict__ out)       // (B,)
{
    const int s = blockIdx.x * 64 + (int)threadIdx.x;

    constexpr float Hs = 0.01f;
    constexpr float Ad = 1.0f - 2.0f * Hs;          // 0.98
    constexpr float Rc = 0.1f;
    constexpr float SC = -1.44269504088896340736f;  // -log2(e)

    const float k1 = K[0], k2 = K[1];

    // upper-tri fold of L, pre-scaled into exp2 domain
    const float u11 = L[0] * SC;
    const float u12 = (L[1] + L[4]) * SC;
    const float u13 = (L[2] + L[8]) * SC;
    const float u14 = (L[3] + L[12]) * SC;
    const float u22 = L[5] * SC;
    const float u23 = (L[6] + L[9]) * SC;
    const float u24 = (L[7] + L[13]) * SC;
    const float u33 = L[10] * SC;
    const float u34 = (L[11] + L[14]) * SC;
    const float u44 = L[15] * SC;

    const v2f Ua  = mk2(u11, u22);
    const v2f Ub  = mk2(u12, 0.0f);   // * x2 (bcast hi of X)
    const v2f Uc  = mk2(u13, u23);    // * h1 (bcast lo of H)
    const v2f Ud  = mk2(u14, u24);    // * h2 (bcast hi of H)
    const v2f Ue  = mk2(u33, u44);
    const v2f Uf  = mk2(u34, 0.0f);   // * h2 (bcast hi of H)
    const v2f M12 = mk2(M[0] * SC, M[1] * SC);
    const v2f M34 = mk2(M[2] * SC, M[3] * SC);
    const float kc = __builtin_amdgcn_exp2f(Mo[0] * SC);  // exp(-c0)

    const v2f AD2  = mk2(Ad, Ad);
    const v2f HS2  = mk2(Hs, Hs);
    const v2f HK2  = mk2(Hs * k1, Hs * k2);
    const v2f NEG1 = mk2(-1.0f, -1.0f);
    const float C1v = 0.5f * Hs * Hs;
    const float C2v = -Hs * Hs;

    // ---- state ----
    v2f X  = mk2(1.0f, 0.0f);     // x0 = (1, 0)
    v2f Hh = X;
    v2f accA = mk2(0.0f, 0.0f);   // {Sum x1^2, Sum x2^2}
    float aXY = 0.0f;             // Sum x1*x2
    float aD  = 0.0f;             // Sum delta
    float phi = __int_as_float(0xff800000u);  // -inf: step 0 -> E=0 -> d=1 exact

    auto step = [&](float w1, float w2, bool cost) {
        float E = __builtin_amdgcn_exp2f(phi);         // exp2-domain phi_t
        float y = fmaf(kc, E, 1.0f);
        float d = __builtin_amdgcn_rcpf(y);            // sigmoid(phi_t)
        v2f dX = pk_fma(Hh, NEG1, X);                  // X - H
        v2f Hn; Hn.x = fmaf(d, dX.x, Hh.x); Hn.y = fmaf(d, dX.y, Hh.y);
        v2f P2  = pk_mul(HK2, Hn);
        v2f HU2 = pk_hadd(P2);                         // (Hs*K.h', same)
        v2f Wc; Wc.x = w1 + C1v; Wc.y = w2 + C2v;
        v2f Bv  = pk_add(Wc, HU2);
        v2f Xin = pk_fma_b1swap(HS2, X, Bv);           // Hs*(x2,x1) + Bv
        v2f Xn  = pk_fma(AD2, X, Xin);                 // Ad*(x1,x2) + ...
        if (cost) {                                    // stage cost: PRE-update X
            accA = pk_fma(X, X, accA);
            aXY  = fmaf(X.x, X.y, aXY);
            aD  += d;
        }
        X = Xn; Hh = Hn;
        // phi_{t+1} = z'.(U z' + m) on updated state (c0 folded into kc)
        v2f T12 = pk_fma(Ua, X, M12);                  // (u11 x1+m1, u22 x2+m2)
        T12 = pk_fma_b1hi(Ub, X, T12);                 // +(u12 x2, 0)
        T12 = pk_fma_b1lo(Uc, Hh, T12);                // +(u13 h1, u23 h1)
        T12 = pk_fma_b1hi(Ud, Hh, T12);                // +(u14 h2, u24 h2)
        v2f T34 = pk_fma(Ue, Hh, M34);                 // (u33 h1+m3, u44 h2+m4)
        T34 = pk_fma_b1hi(Uf, Hh, T34);                // +(u34 h2, 0)
        v2f Pp = pk_mul(X, T12);
        Pp = pk_fma(Hh, T34, Pp);
        phi = Pp.x + Pp.y;
    };

    // 8-step chunks (2 float4 per stream), double-buffered
    auto chunk = [&](const float4* b0, const float4* b1, bool lastc) {
        #pragma unroll
        for (int q = 0; q < 2; ++q) {
            float4 a = b0[q];
            float4 b = b1[q];
            step(a.x, b.x, true);
            step(a.y, b.y, true);
            step(a.z, b.z, true);
            step(a.w, b.w, !(lastc && (q == 1)));      // t=T-1: no stage cost
        }
    };

    const float4* r0 = reinterpret_cast<const float4*>(w + (size_t)s * 2 * T_STEPS);
    const float4* r1 = reinterpret_cast<const float4*>(w + (size_t)s * 2 * T_STEPS + T_STEPS);

    float4 A0[2], A1[2], B0[2], B1[2];
    #pragma unroll
    for (int q = 0; q < 2; ++q) { A0[q] = r0[q];     A1[q] = r1[q]; }
    #pragma unroll
    for (int q = 0; q < 2; ++q) { B0[q] = r0[2 + q]; B1[q] = r1[2 + q]; }

    chunk(A0, A1, false);                              // chunk 0

    for (int i = 0; i < 127; ++i) {                    // chunks 1..254
        const float4* p0 = r0 + (size_t)(2 + 2 * i) * 2;
        const float4* p1 = r1 + (size_t)(2 + 2 * i) * 2;
        #pragma unroll
        for (int q = 0; q < 2; ++q) { A0[q] = p0[q]; A1[q] = p1[q]; }
        chunk(B0, B1, false);                          // chunk 1+2i
        const float4* q0 = r0 + (size_t)(3 + 2 * i) * 2;
        const float4* q1 = r1 + (size_t)(3 + 2 * i) * 2;
        #pragma unroll
        for (int q = 0; q < 2; ++q) { B0[q] = q0[q]; B1[q] = q1[q]; }
        chunk(A0, A1, false);                          // chunk 2+2i
    }
    chunk(B0, B1, true);                               // chunk 255 (last: no cost)

    // Sum us^2 = k1^2 Sx1^2 + k2^2 Sx2^2 + 2 k1 k2 Sx1x2
    float us2 = fmaf(k1 * k1, accA.x, fmaf(k2 * k2, accA.y, 2.0f * k1 * k2 * aXY));
    float J = accA.x + accA.y + Rc * us2 + aD
            + 10.0f * fmaf(X.x, X.x, X.y * X.y);       // terminal cost
    out[s] = J;
}

extern "C" void kernel_launch(void* const* d_in, const int* in_sizes, int n_in,
                              void* d_out, int out_size, void* d_ws, size_t ws_size,
                              hipStream_t stream) {
    const float* w  = (const float*)d_in[0];
    const float* K  = (const float*)d_in[1];
    const float* L  = (const float*)d_in[2];
    const float* M  = (const float*)d_in[3];
    const float* Mo = (const float*)d_in[4];
    float* out = (float*)d_out;

    // 8192 samples, 1 lane each = 128 blocks of 64 (1 wave/block)
    hipLaunchKernelGGL(cstr_kernel, dim3(BATCH / 64), dim3(64), 0, stream,
                       w, K, L, M, Mo, out);
}

// Round 10
// 305.684 us; speedup vs baseline: 1.9230x; 1.0231x over previous
//
#include <hip/hip_runtime.h>

// CSTR gated-estimator trajectory cost — 1 lane/sample, minimal scalar VALU.
// B=8192 samples, T=2048 sequential RK4 steps, N=2 states.
//
// Empirical per-wave law (fits R0/R1/R2/R3/R7/R8 within ~3%):
//   cyc/step = 80 (exp+rcp) + 2.6*N_VALU_equiv + 12.75*N_DPP.
// R8 lesson: v_pk_fma_f32 = 4 issue cyc = 2 scalar fmas (fp32 peak is
// 1 FMA/lane/cyc) -> packing is a wash. This version minimizes TRUE scalar
// op count: V=32, DPP=0, trans=2 -> predicted ~163 cyc/step (~139 us).
//
// Math (same liberties as all passing rounds):
//   RK4 collapsed: x1' = .98 x1 + .01 x2 + Hs*u + H^2/2 + w1
//                  x2' = .98 x2 + .01 x1 + Hs*u - H^2   + w2,  u = K.h'
//   h' = h + d*(x-h);  d = sigmoid(phi) = rcp(1 + exp2(phi_s)) where phi_s
//   is the full phi (quad+lin+c0) pre-scaled by SC = -log2(e); c0 folded
//   into the quad-form combine so no separate kc multiply.
//   Step 0: phi = -inf -> E=0 -> d=rcp(1)=1 exact (gate forced open).
//   Cost moments {Sx1^2,Sx2^2,Sx1x2,Sd}; Sum us^2 reconstructed at end.

#define T_STEPS 2048
#define BATCH   8192

__global__ __launch_bounds__(64, 1) void cstr_kernel(
    const float* __restrict__ w,   // (B, 2, T)
    const float* __restrict__ K,   // (1, 2)
    const float* __restrict__ L,   // (4, 4)
    const float* __restrict__ M,   // (1, 4)
    const float* __restrict__ Mo,  // (1, 1)
    float* __restrict__ out)       // (B,)
{
    const int s = blockIdx.x * 64 + (int)threadIdx.x;

    constexpr float Hs = 0.01f;
    constexpr float Ad = 1.0f - 2.0f * Hs;          // 0.98
    constexpr float Rc = 0.1f;
    constexpr float SC = -1.44269504088896340736f;  // -log2(e)

    const float k1 = K[0], k2 = K[1];

    // upper-tri fold of L, pre-scaled into exp2 domain
    const float u11 = L[0] * SC;
    const float u12 = (L[1] + L[4]) * SC;
    const float u13 = (L[2] + L[8]) * SC;
    const float u14 = (L[3] + L[12]) * SC;
    const float u22 = L[5] * SC;
    const float u23 = (L[6] + L[9]) * SC;
    const float u24 = (L[7] + L[13]) * SC;
    const float u33 = L[10] * SC;
    const float u34 = (L[11] + L[14]) * SC;
    const float u44 = L[15] * SC;
    const float m1s = M[0] * SC, m2s = M[1] * SC, m3s = M[2] * SC, m4s = M[3] * SC;
    const float c0s = Mo[0] * SC;

    const float hk1 = Hs * k1, hk2 = Hs * k2;
    const float C1v = 0.5f * Hs * Hs;               // +H^2/2
    const float C21 = -Hs * Hs - C1v;               // C2 - C1 = -1.5*H^2

    // ---- state ----
    float x1 = 1.0f, x2 = 0.0f;   // x0 = (1, 0)
    float h1 = x1, h2 = x2;
    float dx1 = 0.0f, dx2 = 0.0f;
    float phi = __int_as_float(0xff800000u);  // -inf: step 0 -> E=0 -> d=1
    float aA1 = 0.0f, aA2 = 0.0f;  // Sum x1^2, Sum x2^2
    float aXY = 0.0f;              // Sum x1*x2
    float aD  = 0.0f;              // Sum delta

    auto step = [&](float w1, float w2, bool cost) {
        float E = __builtin_amdgcn_exp2f(phi);          // exp(-phi_full)
        float d = __builtin_amdgcn_rcpf(1.0f + E);      // sigmoid(phi)
        // estimator update
        h1 = fmaf(d, dx1, h1);
        h2 = fmaf(d, dx2, h2);
        // control + per-state drift:  hu1 = Hs*u + C1, hu2 = Hs*u + C2
        float t   = fmaf(hk1, h1, C1v);
        float hu1 = fmaf(hk2, h2, t);
        float hu2 = hu1 + C21;
        float b1  = w1 + hu1;
        float b2  = w2 + hu2;
        if (cost) {                   // stage cost uses PRE-update x, this d
            aA1 = fmaf(x1, x1, aA1);
            aA2 = fmaf(x2, x2, aA2);
            aXY = fmaf(x1, x2, aXY);
            aD += d;
        }
        float nx1 = fmaf(Ad, x1, fmaf(Hs, x2, b1));
        float nx2 = fmaf(Ad, x2, fmaf(Hs, x1, b2));
        x1 = nx1; x2 = nx2;
        dx1 = x1 - h1;
        dx2 = x2 - h2;
        // phi for next step: z.(U z) + m.z + c0 on updated z=(x1,x2,h1,h2)
        float t1 = fmaf(u11, x1, m1s);
        t1 = fmaf(u12, x2, t1);
        t1 = fmaf(u13, h1, t1);
        t1 = fmaf(u14, h2, t1);
        float t2 = fmaf(u22, x2, m2s);
        t2 = fmaf(u23, h1, t2);
        t2 = fmaf(u24, h2, t2);
        float t3 = fmaf(u33, h1, m3s);
        t3 = fmaf(u34, h2, t3);
        float t4 = fmaf(u44, h2, m4s);
        float pp = fmaf(x1, t1, c0s);
        pp = fmaf(x2, t2, pp);
        pp = fmaf(h1, t3, pp);
        phi = fmaf(h2, t4, pp);
    };

    // 8-step chunks (2 float4 per stream), double-buffered
    auto chunk = [&](const float4* b0, const float4* b1, bool lastc) {
        #pragma unroll
        for (int q = 0; q < 2; ++q) {
            float4 a = b0[q];
            float4 b = b1[q];
            step(a.x, b.x, true);
            step(a.y, b.y, true);
            step(a.z, b.z, true);
            step(a.w, b.w, !(lastc && (q == 1)));      // t=T-1: no stage cost
        }
    };

    const float4* r0 = reinterpret_cast<const float4*>(w + (size_t)s * 2 * T_STEPS);
    const float4* r1 = reinterpret_cast<const float4*>(w + (size_t)s * 2 * T_STEPS + T_STEPS);

    float4 A0[2], A1[2], B0[2], B1[2];
    #pragma unroll
    for (int q = 0; q < 2; ++q) { A0[q] = r0[q];     A1[q] = r1[q]; }
    #pragma unroll
    for (int q = 0; q < 2; ++q) { B0[q] = r0[2 + q]; B1[q] = r1[2 + q]; }

    chunk(A0, A1, false);                              // chunk 0

    for (int i = 0; i < 127; ++i) {                    // chunks 1..254
        const float4* p0 = r0 + (size_t)(2 + 2 * i) * 2;
        const float4* p1 = r1 + (size_t)(2 + 2 * i) * 2;
        #pragma unroll
        for (int q = 0; q < 2; ++q) { A0[q] = p0[q]; A1[q] = p1[q]; }
        chunk(B0, B1, false);                          // chunk 1+2i
        const float4* q0 = r0 + (size_t)(3 + 2 * i) * 2;
        const float4* q1 = r1 + (size_t)(3 + 2 * i) * 2;
        #pragma unroll
        for (int q = 0; q < 2; ++q) { B0[q] = q0[q]; B1[q] = q1[q]; }
        chunk(A0, A1, false);                          // chunk 2+2i
    }
    chunk(B0, B1, true);                               // chunk 255 (last: no cost)

    // Sum us^2 = k1^2 Sx1^2 + k2^2 Sx2^2 + 2 k1 k2 Sx1x2
    float us2 = fmaf(k1 * k1, aA1, fmaf(k2 * k2, aA2, 2.0f * k1 * k2 * aXY));
    float J = aA1 + aA2 + Rc * us2 + aD
            + 10.0f * fmaf(x1, x1, x2 * x2);           // terminal cost
    out[s] = J;
}

extern "C" void kernel_launch(void* const* d_in, const int* in_sizes, int n_in,
                              void* d_out, int out_size, void* d_ws, size_t ws_size,
                              hipStream_t stream) {
    const float* w  = (const float*)d_in[0];
    const float* K  = (const float*)d_in[1];
    const float* L  = (const float*)d_in[2];
    const float* M  = (const float*)d_in[3];
    const float* Mo = (const float*)d_in[4];
    float* out = (float*)d_out;

    // 8192 samples, 1 lane each = 128 blocks of 64 (1 wave/block)
    hipLaunchKernelGGL(cstr_kernel, dim3(BATCH / 64), dim3(64), 0, stream,
                       w, K, L, M, Mo, out);
}